// Round 3
// baseline (864.206 us; speedup 1.0000x reference)
//
#include <hip/hip_runtime.h>
#include <float.h>

// PretrainingGIN on MI355X — Round 3: linked-list edge grouping (no counting
// sort). R2's k_scatter burned 127us / 105MB HBM writes on random 4B stores;
// replaced by sequential int2 (next,src) list writes + 400KB head atomics.
// - k_agg: wave/node, chases the list; nxt load + row gather overlap, BW-bound
//   on the 410MB/layer row gather (L2/L3-served).
// - k_mlp: fused 2-GEMM bf16 MFMA (unchanged from R2).

#define N_NODES 100000
#define N_EDGES 1600000
#define DIM 128
#define NGRAPHS 64

#define MROWS 128          // rows per MLP block (2 row-tiles of 64)
#define LSTRIDE 136        // bf16 elems; 272B rows keep 16B align

typedef __attribute__((ext_vector_type(8))) short bf16x8;
typedef __attribute__((ext_vector_type(4))) float f32x4;

__device__ inline float bflo(unsigned u) { return __uint_as_float(u << 16); }
__device__ inline float bfhi(unsigned u) { return __uint_as_float(u & 0xffff0000u); }

__device__ inline unsigned short f2bf(float a) {      // RNE
    unsigned u = __float_as_uint(a);
    u = u + 0x7fff + ((u >> 16) & 1);
    return (unsigned short)(u >> 16);
}
__device__ inline unsigned f2bf_pack(float a, float b) {
    unsigned ua = __float_as_uint(a), ub = __float_as_uint(b);
    ua = ua + 0x7fff + ((ua >> 16) & 1);
    ub = ub + 0x7fff + ((ub >> 16) & 1);
    return (ua >> 16) | (ub & 0xffff0000u);
}

// ---------------- edge linked-list build ----------------
__global__ void k_init_head(int* __restrict__ head) {
    int i = blockIdx.x * blockDim.x + threadIdx.x;
    if (i < N_NODES) head[i] = -1;
}

// nxt[e] = (previous head of dst[e], src[e]); head[dst[e]] = e.
// nxt writes are fully sequential (12.8MB streamed); only head is random.
__global__ void k_build(const int* __restrict__ src, const int* __restrict__ dst,
                        int* __restrict__ head, int2* __restrict__ nxt) {
    int e = blockIdx.x * blockDim.x + threadIdx.x;
    if (e < N_EDGES) {
        int s = src[e];
        int old = atomicExch(&head[dst[e]], e);
        nxt[e] = make_int2(old, s);
    }
}

// ---------------- dtype prep ----------------
__global__ void k_cast(const float* __restrict__ x, unsigned short* __restrict__ y) {
    int i = (blockIdx.x * blockDim.x + threadIdx.x) * 4;
    if (i < N_NODES * DIM) {
        float4 v = *(const float4*)(x + i);
        uint2 o;
        o.x = f2bf_pack(v.x, v.y);
        o.y = f2bf_pack(v.z, v.w);
        *(uint2*)(y + i) = o;
    }
}

// Repack W (k-major 128x128 fp32) into B-fragment order bf16:
// pack[mat][kb*4096 + c*32 + q*8 + j] = W[mat][(kb*32 + q*8 + j)*128 + c]
__global__ void k_pack(const float* __restrict__ W1, const float* __restrict__ W2,
                       unsigned short* __restrict__ pack) {
    int tid = blockIdx.x * blockDim.x + threadIdx.x;
    if (tid >= 6 * DIM * DIM) return;
    int mat = tid >> 14;           // 0..5 : W1 l0..2, W2 l0..2
    int e = tid & 16383;
    int k = e >> 7, c = e & 127;
    const float* W = (mat < 3) ? (W1 + mat * DIM * DIM) : (W2 + (mat - 3) * DIM * DIM);
    int kb = k >> 5, q = (k >> 3) & 3, j = k & 7;
    pack[mat * DIM * DIM + kb * 4096 + c * 32 + q * 8 + j] = f2bf(W[k * DIM + c]);
}

// ---------------- aggregation: m[i] = h[i] + sum_{j->i} h[j] ----------------
__global__ __launch_bounds__(256) void k_agg(const unsigned short* __restrict__ h,
                                             const int* __restrict__ head,
                                             const int2* __restrict__ nxt,
                                             unsigned short* __restrict__ m) {
    int gid = blockIdx.x * blockDim.x + threadIdx.x;
    int w = gid >> 6;
    int lane = gid & 63;
    if (w >= N_NODES) return;
    int col = lane * 2;
    size_t rb = (size_t)w * DIM + col;
    unsigned u = *(const unsigned*)(h + rb);
    float ax = bflo(u), ay = bfhi(u);
    int e = head[w];
    while (e >= 0) {
        int2 p = nxt[e];           // (next, src) — one 8B load per step
        unsigned v = *(const unsigned*)(h + (size_t)p.y * DIM + col);
        ax += bflo(v);
        ay += bfhi(v);
        e = p.x;
    }
    *(unsigned*)(m + rb) = f2bf_pack(ax, ay);
}

// ---------------- fused MLP on MFMA ----------------
// h_out = [relu]( relu(m@W1 + b1) @ W2 + b2 ), in-place safe per block.
__global__ __launch_bounds__(256) void k_mlp(const unsigned short* __restrict__ m,
                                             unsigned short* __restrict__ hout,
                                             const unsigned short* __restrict__ Wp1,
                                             const float* __restrict__ b1,
                                             const unsigned short* __restrict__ Wp2,
                                             const float* __restrict__ b2,
                                             int relu_out) {
    __shared__ unsigned short t1[MROWS * LSTRIDE];   // 34816 B
    const int tid = threadIdx.x;
    const int wv = tid >> 6, lane = tid & 63;
    const int q = lane >> 4, n = lane & 15;
    const int row0 = blockIdx.x * MROWS;

    // A1 fragments: 2 row-tiles x 4 k-blocks, each 16B contiguous from global m
    bf16x8 a1[2][4];
#pragma unroll
    for (int s = 0; s < 2; ++s) {
        int grow = row0 + s * 64 + wv * 16 + n;
        if (grow >= N_NODES) grow = N_NODES - 1;   // stores masked later
        const unsigned short* mr = m + (size_t)grow * DIM + q * 8;
#pragma unroll
        for (int kb = 0; kb < 4; ++kb)
            a1[s][kb] = *(const bf16x8*)(mr + kb * 32);
    }

    float bia1[8], bia2[8];
#pragma unroll
    for (int ct = 0; ct < 8; ++ct) {
        bia1[ct] = b1[ct * 16 + n];
        bia2[ct] = b2[ct * 16 + n];
    }

    // GEMM1: t = relu(m@W1 + b1) -> LDS (wave-private rows; no barrier needed)
#pragma unroll
    for (int ct = 0; ct < 8; ++ct) {
        f32x4 acc0 = {0.f, 0.f, 0.f, 0.f};
        f32x4 acc1 = {0.f, 0.f, 0.f, 0.f};
#pragma unroll
        for (int kb = 0; kb < 4; ++kb) {
            bf16x8 b = *(const bf16x8*)(Wp1 + kb * 4096 + (ct * 16 + n) * 32 + q * 8);
            acc0 = __builtin_amdgcn_mfma_f32_16x16x32_bf16(a1[0][kb], b, acc0, 0, 0, 0);
            acc1 = __builtin_amdgcn_mfma_f32_16x16x32_bf16(a1[1][kb], b, acc1, 0, 0, 0);
        }
#pragma unroll
        for (int r = 0; r < 4; ++r) {
            int lr = wv * 16 + q * 4 + r;
            t1[lr * LSTRIDE + ct * 16 + n]        = f2bf(fmaxf(acc0[r] + bia1[ct], 0.f));
            t1[(64 + lr) * LSTRIDE + ct * 16 + n] = f2bf(fmaxf(acc1[r] + bia1[ct], 0.f));
        }
    }

    // A2 fragments from LDS (same wave's rows; compiler orders via lgkmcnt)
    bf16x8 a2[2][4];
#pragma unroll
    for (int s = 0; s < 2; ++s) {
        const unsigned short* tr = t1 + (s * 64 + wv * 16 + n) * LSTRIDE + q * 8;
#pragma unroll
        for (int kb = 0; kb < 4; ++kb)
            a2[s][kb] = *(const bf16x8*)(tr + kb * 32);
    }

    // GEMM2: out = t@W2 + b2 -> back into t1 (wave-private rows)
#pragma unroll
    for (int ct = 0; ct < 8; ++ct) {
        f32x4 acc0 = {0.f, 0.f, 0.f, 0.f};
        f32x4 acc1 = {0.f, 0.f, 0.f, 0.f};
#pragma unroll
        for (int kb = 0; kb < 4; ++kb) {
            bf16x8 b = *(const bf16x8*)(Wp2 + kb * 4096 + (ct * 16 + n) * 32 + q * 8);
            acc0 = __builtin_amdgcn_mfma_f32_16x16x32_bf16(a2[0][kb], b, acc0, 0, 0, 0);
            acc1 = __builtin_amdgcn_mfma_f32_16x16x32_bf16(a2[1][kb], b, acc1, 0, 0, 0);
        }
#pragma unroll
        for (int r = 0; r < 4; ++r) {
            int lr = wv * 16 + q * 4 + r;
            float v0 = acc0[r] + bia2[ct];
            float v1 = acc1[r] + bia2[ct];
            if (relu_out) { v0 = fmaxf(v0, 0.f); v1 = fmaxf(v1, 0.f); }
            t1[lr * LSTRIDE + ct * 16 + n]        = f2bf(v0);
            t1[(64 + lr) * LSTRIDE + ct * 16 + n] = f2bf(v1);
        }
    }
    __syncthreads();

    // coalesced store-back: thread -> row tid>>1, 64-col half (tid&1)
    {
        int r = tid >> 1;
        int c0 = (tid & 1) * 64;
        int grow = row0 + r;
        if (grow < N_NODES) {
            unsigned short* dp = hout + (size_t)grow * DIM + c0;
            const unsigned short* sp = t1 + r * LSTRIDE + c0;
#pragma unroll
            for (int s8 = 0; s8 < 8; ++s8)
                *(bf16x8*)(dp + s8 * 8) = *(const bf16x8*)(sp + s8 * 8);
        }
    }
}

// ---------------- pool ----------------
__global__ void k_starts(const int* __restrict__ batch, int* __restrict__ starts) {
    int g = threadIdx.x;
    if (g > NGRAPHS) return;
    int lo = 0, hi = N_NODES;
    while (lo < hi) {
        int mid = (lo + hi) >> 1;
        if (batch[mid] < g) lo = mid + 1;
        else hi = mid;
    }
    starts[g] = lo;
}

__global__ __launch_bounds__(256) void k_pool(const unsigned short* __restrict__ h,
                                              const int* __restrict__ starts,
                                              float* __restrict__ out) {
    __shared__ float red[4][DIM];
    int g = blockIdx.x;
    int t = threadIdx.x;
    int rowpar = t >> 6;           // 0..3
    int col = (t & 63) * 2;
    int i0 = starts[g], i1 = starts[g + 1];
    float mx = -FLT_MAX, my = -FLT_MAX;
    for (int i = i0 + rowpar; i < i1; i += 4) {
        unsigned u = *(const unsigned*)(h + (size_t)i * DIM + col);
        mx = fmaxf(mx, bflo(u));
        my = fmaxf(my, bfhi(u));
    }
    red[rowpar][col] = mx;
    red[rowpar][col + 1] = my;
    __syncthreads();
    if (rowpar == 0) {
        mx = fmaxf(fmaxf(red[0][col], red[1][col]), fmaxf(red[2][col], red[3][col]));
        my = fmaxf(fmaxf(red[0][col + 1], red[1][col + 1]),
                   fmaxf(red[2][col + 1], red[3][col + 1]));
        out[g * DIM + col] = mx;
        out[g * DIM + col + 1] = my;
    }
}

extern "C" void kernel_launch(void* const* d_in, const int* in_sizes, int n_in,
                              void* d_out, int out_size, void* d_ws, size_t ws_size,
                              hipStream_t stream) {
    const float* x   = (const float*)d_in[0];
    const int* ei    = (const int*)d_in[1];
    const int* batch = (const int*)d_in[2];
    const float* W1  = (const float*)d_in[3];
    const float* b1  = (const float*)d_in[4];
    const float* W2  = (const float*)d_in[5];
    const float* b2  = (const float*)d_in[6];
    float* out = (float*)d_out;

    const int* src = ei;
    const int* dst = ei + N_EDGES;

    unsigned short* hA  = (unsigned short*)d_ws;                  // 25.6 MB
    unsigned short* hB  = hA + (size_t)N_NODES * DIM;             // 25.6 MB
    int2* nxt           = (int2*)(hB + (size_t)N_NODES * DIM);    // 12.8 MB
    int* head           = (int*)(nxt + N_EDGES);                  // 400 KB
    unsigned short* wpk = (unsigned short*)(head + N_NODES);      // 192 KB
    int* starts         = (int*)(wpk + 6 * DIM * DIM);            // 65 ints

    // edge list build (replaces R2's zero+hist+3 scans+scatter)
    k_init_head<<<(N_NODES + 255) / 256, 256, 0, stream>>>(head);
    k_build<<<(N_EDGES + 255) / 256, 256, 0, stream>>>(src, dst, head, nxt);

    // dtype prep
    k_cast<<<(N_NODES * DIM / 4 + 255) / 256, 256, 0, stream>>>(x, hA);
    k_pack<<<(6 * DIM * DIM + 255) / 256, 256, 0, stream>>>(W1, W2, wpk);

    const int aggBlocks = N_NODES / 4;       // wave per node
    const int mlpBlocks = (N_NODES + MROWS - 1) / MROWS;

    unsigned short* Wp1 = wpk;               // W1 layers 0..2
    unsigned short* Wp2 = wpk + 3 * DIM * DIM;

    // layer 0: hA -> m=hB -> h=hB
    k_agg<<<aggBlocks, 256, 0, stream>>>(hA, head, nxt, hB);
    k_mlp<<<mlpBlocks, 256, 0, stream>>>(hB, hB, Wp1, b1, Wp2, b2, 1);
    // layer 1: hB -> m=hA -> h=hA
    k_agg<<<aggBlocks, 256, 0, stream>>>(hB, head, nxt, hA);
    k_mlp<<<mlpBlocks, 256, 0, stream>>>(hA, hA, Wp1 + DIM * DIM, b1 + DIM,
                                         Wp2 + DIM * DIM, b2 + DIM, 1);
    // layer 2: hA -> m=hB -> h=hB (no trailing relu)
    k_agg<<<aggBlocks, 256, 0, stream>>>(hA, head, nxt, hB);
    k_mlp<<<mlpBlocks, 256, 0, stream>>>(hB, hB, Wp1 + 2 * DIM * DIM, b1 + 2 * DIM,
                                         Wp2 + 2 * DIM * DIM, b2 + 2 * DIM, 0);

    // pool
    k_starts<<<1, 128, 0, stream>>>(batch, starts);
    k_pool<<<NGRAPHS, 256, 0, stream>>>(hB, starts, out);
}